// Round 2
// baseline (1428.263 us; speedup 1.0000x reference)
//
#include <hip/hip_runtime.h>

// DIMKT: B=1024, S=200, D=128.
// R2: scan has ZERO per-step LDS gathers and all global loads software-
// pipelined in registers; barriers are lgkm-only (asm) so prefetches stay in
// flight; y-dot reduction deferred to overlap next step's MFMA issue.
// gpre (corr/qd/cd gate bias) precomputed per (t,b) as a bf16 stream.

#define S_LEN 200
#define NBATCH 1024
#define DIM 128
#define LOG2E 1.4426950408889634f

typedef short short8 __attribute__((ext_vector_type(8)));
typedef float f32x4 __attribute__((ext_vector_type(4)));

__device__ __forceinline__ unsigned short f2b(float f) {
  union { float f; unsigned u; } v; v.f = f;
  unsigned r = (v.u + 0x7FFFu + ((v.u >> 16) & 1u)) >> 16;  // RNE
  return (unsigned short)r;
}
__device__ __forceinline__ float b2f(unsigned short b) {
  union { unsigned u; float f; } v; v.u = ((unsigned)b) << 16;
  return v.f;
}
__device__ __forceinline__ float fast_sigmoid(float x) {
  return __builtin_amdgcn_rcpf(1.0f + __builtin_amdgcn_exp2f(-LOG2E * x));
}
__device__ __forceinline__ float fast_tanh(float x) {
  return 2.0f * __builtin_amdgcn_rcpf(1.0f + __builtin_amdgcn_exp2f(-2.0f * LOG2E * x)) - 1.0f;
}
// LDS-only barrier: does NOT drain vmcnt, so global prefetches stay in flight.
__device__ __forceinline__ void wg_barrier_lds() {
  __asm__ volatile("s_waitcnt lgkmcnt(0)\n\ts_barrier" ::: "memory");
}

// ---------------- P1: projected embedding tables: T[r][o] = sum_k E[r][k] * W[o][coff+k]
__global__ void proj_table_kernel(const float* __restrict__ E, int M,
                                  const float* __restrict__ W, int ldw, int coff,
                                  unsigned short* __restrict__ T) {
  __shared__ __align__(16) float Elds[32][132];
  const int r0 = blockIdx.x * 32;
  for (int idx = threadIdx.x; idx < 32 * 32; idx += 256) {
    const int r = idx >> 5, c4 = idx & 31;
    float4 v = {0.f, 0.f, 0.f, 0.f};
    if (r0 + r < M) v = *(const float4*)(E + (size_t)(r0 + r) * DIM + c4 * 4);
    *(float4*)&Elds[r][c4 * 4] = v;
  }
  __syncthreads();
  const int o = threadIdx.x & 127, rg = threadIdx.x >> 7;
  const float* Wrow = W + (size_t)o * ldw + coff;
  float acc[16];
#pragma unroll
  for (int i = 0; i < 16; ++i) acc[i] = 0.f;
  for (int k4 = 0; k4 < 32; ++k4) {
    const float4 wv = *(const float4*)(Wrow + k4 * 4);
#pragma unroll
    for (int rr = 0; rr < 16; ++rr) {
      const float4 ev = *(const float4*)&Elds[rg * 16 + rr][k4 * 4];
      acc[rr] = fmaf(wv.x, ev.x, acc[rr]);
      acc[rr] = fmaf(wv.y, ev.y, acc[rr]);
      acc[rr] = fmaf(wv.z, ev.z, acc[rr]);
      acc[rr] = fmaf(wv.w, ev.w, acc[rr]);
    }
  }
#pragma unroll
  for (int rr = 0; rr < 16; ++rr) {
    const int r = r0 + rg * 16 + rr;
    if (r < M) T[(size_t)r * DIM + o] = f2b(acc[rr]);
  }
}

// ---------------- P1b: tiny gate-bias tables
__global__ void small_tables_kernel(const float* __restrict__ Eqd, const float* __restrict__ Ecd,
                                    const float* __restrict__ Ecorr,
                                    const float* __restrict__ Wp1, const float* __restrict__ bp1,
                                    const float* __restrict__ Wp2, const float* __restrict__ bp2,
                                    const float* __restrict__ Wk, const float* __restrict__ bk,
                                    unsigned short* __restrict__ Tkqd, unsigned short* __restrict__ Tkcd,
                                    float* __restrict__ Tkc, float* __restrict__ Tp1c,
                                    float* __restrict__ Tp2c) {
  const int blk = blockIdx.x;
  const int tid = threadIdx.x;
  if (blk < 101) {
    const int o = tid & 127, half = tid >> 7;
    const float* e = (half ? Ecd : Eqd) + (size_t)blk * DIM;
    const float* wr = Wk + (size_t)o * 512 + (half ? 384 : 256);
    float a = 0.f;
    for (int k = 0; k < DIM; ++k) a = fmaf(e[k], wr[k], a);
    (half ? Tkcd : Tkqd)[blk * DIM + o] = f2b(a);
  } else {
    for (int idx = tid; idx < 768; idx += 256) {
      const int t = idx >> 8, e = (idx >> 7) & 1, o = idx & 127;
      const float* ec = Ecorr + e * DIM;
      const float* wr;
      float bias;
      float* dst;
      if (t == 0)      { wr = Wp1 + (size_t)o * 256 + 128; bias = bp1[o]; dst = Tp1c; }
      else if (t == 1) { wr = Wp2 + (size_t)o * 256 + 128; bias = bp2[o]; dst = Tp2c; }
      else             { wr = Wk  + (size_t)o * 512 + 128; bias = bk[o];  dst = Tkc;  }
      float a = bias;
      for (int k = 0; k < DIM; ++k) a = fmaf(ec[k], wr[k], a);
      dst[e * DIM + o] = a;
    }
  }
}

// ---------------- P2: x[s][b][:] = Tq[q]+Tc[c]+Tqd[qd]+Tcd[cd]+bx (bf16, s-major)
__global__ void build_x_kernel(const int* __restrict__ qs, const int* __restrict__ cs,
                               const int* __restrict__ qds, const int* __restrict__ cds,
                               const unsigned short* __restrict__ Tq, const unsigned short* __restrict__ Tc,
                               const unsigned short* __restrict__ Tqd, const unsigned short* __restrict__ Tcd,
                               const float* __restrict__ bx, unsigned short* __restrict__ xg) {
  const int r = blockIdx.x * 16 + (threadIdx.x >> 4);   // r = s*1024 + b
  const int c8 = (threadIdx.x & 15) * 8;
  const int s = r >> 10, b = r & 1023;
  const int q = qs[b * S_LEN + s], c = cs[b * S_LEN + s];
  const int qd = qds[b * S_LEN + s], cd = cds[b * S_LEN + s];
  union U8 { uint4 v; unsigned short s[8]; };
  U8 vq, vc, vd, ve, o;
  vq.v = *(const uint4*)(Tq + (size_t)q * DIM + c8);
  vc.v = *(const uint4*)(Tc + (size_t)c * DIM + c8);
  vd.v = *(const uint4*)(Tqd + (size_t)qd * DIM + c8);
  ve.v = *(const uint4*)(Tcd + (size_t)cd * DIM + c8);
  const float4 bx0 = *(const float4*)(bx + c8);
  const float4 bx1 = *(const float4*)(bx + c8 + 4);
  float bb[8] = {bx0.x, bx0.y, bx0.z, bx0.w, bx1.x, bx1.y, bx1.z, bx1.w};
#pragma unroll
  for (int j = 0; j < 8; ++j) {
    const float sv = b2f(vq.s[j]) + b2f(vc.s[j]) + b2f(vd.s[j]) + b2f(ve.s[j]) + bb[j];
    o.s[j] = f2b(sv);
  }
  *(uint4*)(xg + (size_t)r * DIM + c8) = o.v;
}

// ---------------- P2b: gpre[t][b][:] = Tkc[corr]+Tkqd[qd]+Tkcd[cd] (bf16, t-major)
__global__ void build_gpre_kernel(const int* __restrict__ corr, const int* __restrict__ qds,
                                  const int* __restrict__ cds,
                                  const float* __restrict__ Tkc,
                                  const unsigned short* __restrict__ Tkqd,
                                  const unsigned short* __restrict__ Tkcd,
                                  unsigned short* __restrict__ gg) {
  const int r = blockIdx.x * 16 + (threadIdx.x >> 4);   // r = t*1024 + b, t<=198
  const int c8 = (threadIdx.x & 15) * 8;
  const int t = r >> 10, b = r & 1023;
  const int ci = corr[b * S_LEN + t], qi = qds[b * S_LEN + t], di = cds[b * S_LEN + t];
  union U8 { uint4 v; unsigned short s[8]; };
  U8 vq, vc, o;
  vq.v = *(const uint4*)(Tkqd + (size_t)qi * DIM + c8);
  vc.v = *(const uint4*)(Tkcd + (size_t)di * DIM + c8);
  const float4 k0 = *(const float4*)(Tkc + (size_t)ci * DIM + c8);
  const float4 k1 = *(const float4*)(Tkc + (size_t)ci * DIM + c8 + 4);
  float kk[8] = {k0.x, k0.y, k0.z, k0.w, k1.x, k1.y, k1.z, k1.w};
#pragma unroll
  for (int j = 0; j < 8; ++j) o.s[j] = f2b(kk[j] + b2f(vq.s[j]) + b2f(vc.s[j]));
  *(uint4*)(gg + (size_t)r * DIM + c8) = o.v;
}

// ---------------- P3: the recurrence. 64 blocks x 16 rows, 4 waves (32 cols each).
__global__ __launch_bounds__(256, 1) void scan_kernel(
    const unsigned short* __restrict__ xg,    // [S][B][D] bf16
    const unsigned short* __restrict__ gg,    // [S-1][B][D] bf16
    const float* __restrict__ h0,
    const float* __restrict__ Ws1, const float* __restrict__ bs1,
    const float* __restrict__ Ws2, const float* __restrict__ bs2,
    const float* __restrict__ Wp1, const float* __restrict__ Wp2,
    const float* __restrict__ Wk,
    const float* __restrict__ gTp1c, const float* __restrict__ gTp2c,
    const int* __restrict__ corr_seq,
    float* __restrict__ outp) {
  __shared__ __align__(16) unsigned short Sbuf[16][136];  // s_in (bf16), +pad
  __shared__ __align__(16) unsigned short Hbuf[16][136];  // h (bf16)
  __shared__ __align__(16) unsigned short Pbuf[16][136];  // sdf; pad = dot partials

  const int tid = threadIdx.x;
  const int w = tid >> 6, L = tid & 63, q = L >> 4, m = L & 15;
  const int rbase = blockIdx.x << 4;

  // register-resident B-fragments of the 5 in-scan weights (bf16)
  short8 wf[5][2][4];
  {
    const float* Wptr[5] = {Ws1, Ws2, Wp1, Wp2, Wk};
    const int ldw[5] = {128, 128, 256, 256, 512};
#pragma unroll
    for (int M = 0; M < 5; ++M) {
#pragma unroll
      for (int T = 0; T < 2; ++T) {
        const int n = 32 * w + 16 * T + m;
#pragma unroll
        for (int kb = 0; kb < 4; ++kb) {
          const float* src = Wptr[M] + (size_t)n * ldw[M] + kb * 32 + q * 8;
          const float4 v0 = *(const float4*)src;
          const float4 v1 = *(const float4*)(src + 4);
          short8 f;
          f[0] = (short)f2b(v0.x); f[1] = (short)f2b(v0.y);
          f[2] = (short)f2b(v0.z); f[3] = (short)f2b(v0.w);
          f[4] = (short)f2b(v1.x); f[5] = (short)f2b(v1.y);
          f[6] = (short)f2b(v1.z); f[7] = (short)f2b(v1.w);
          wf[M][T][kb] = f;
        }
      }
    }
  }

  float bs1v[2], bs2v[2], tp1v[2][2], tp2v[2][2];  // [corr][T]
#pragma unroll
  for (int T = 0; T < 2; ++T) {
    const int col = 32 * w + 16 * T + m;
    bs1v[T] = bs1[col];
    bs2v[T] = bs2[col];
    tp1v[0][T] = gTp1c[col];       tp1v[1][T] = gTp1c[DIM + col];
    tp2v[0][T] = gTp2c[col];       tp2v[1][T] = gTp2c[DIM + col];
  }

  // init h (fp32 regs, C-layout), Hbuf, Sbuf = x[0]-h
  float h[2][4];
#pragma unroll
  for (int T = 0; T < 2; ++T) {
    const int col = 32 * w + 16 * T + m;
#pragma unroll
    for (int i = 0; i < 4; ++i) {
      const int row = q * 4 + i;
      const int b = rbase + row;
      const float hv = h0[(size_t)b * DIM + col];
      h[T][i] = hv;
      const float xt = b2f(xg[(size_t)b * DIM + col]);  // s=0
      Hbuf[row][col] = f2b(hv);
      Sbuf[row][col] = f2b(xt - hv);
    }
  }
  if (tid < 16) outp[(size_t)(rbase + tid) * S_LEN + (S_LEN - 1)] = 0.0f;

  // prefetch state: xnb[buf] = x[t+1] (2-deep), ggb[buf] = gg[t] (2-deep), corr idx (1-deep)
  unsigned short xnb[2][2][4], ggb[2][2][4];
  int cin_cur[4], cin_nxt[4];
#pragma unroll
  for (int T = 0; T < 2; ++T) {
    const int col = 32 * w + 16 * T + m;
#pragma unroll
    for (int i = 0; i < 4; ++i) {
      const int b = rbase + q * 4 + i;
      xnb[1][T][i] = xg[((size_t)1 * NBATCH + b) * DIM + col];   // x[1]
      ggb[0][T][i] = gg[((size_t)0 * NBATCH + b) * DIM + col];   // gg[0]
    }
  }
#pragma unroll
  for (int i = 0; i < 4; ++i) cin_cur[i] = corr_seq[(rbase + q * 4 + i) * S_LEN + 0];

  float dotp[4] = {0.f, 0.f, 0.f, 0.f};
  wg_barrier_lds();

  for (int t = 0; t < S_LEN - 1; ++t) {
    // issue prefetches (consumed next iteration; stay in flight across barriers)
    const int txn = (t + 2 < S_LEN) ? t + 2 : S_LEN - 1;
    const int tgg = (t + 1 < S_LEN - 1) ? t + 1 : S_LEN - 2;
#pragma unroll
    for (int T = 0; T < 2; ++T) {
      const int col = 32 * w + 16 * T + m;
#pragma unroll
      for (int i = 0; i < 4; ++i) {
        const int b = rbase + q * 4 + i;
        xnb[t & 1][T][i] = xg[((size_t)txn * NBATCH + b) * DIM + col];
        ggb[(t + 1) & 1][T][i] = gg[((size_t)tgg * NBATCH + b) * DIM + col];
      }
    }
#pragma unroll
    for (int i = 0; i < 4; ++i) cin_nxt[i] = corr_seq[(rbase + q * 4 + i) * S_LEN + tgg];

    // deferred y_{t-1}: reduce prev step's dot partials (overlaps MFMA issue)
    float dr[4] = {dotp[0], dotp[1], dotp[2], dotp[3]};
#pragma unroll
    for (int off = 1; off <= 8; off <<= 1) {
#pragma unroll
      for (int i = 0; i < 4; ++i) dr[i] += __shfl_xor(dr[i], off, 64);
    }
    if (m == 0) {
#pragma unroll
      for (int i = 0; i < 4; ++i) *(float*)&Pbuf[q * 4 + i][128 + 2 * w] = dr[i];
    }

    // phase A: a1 = s_in@Ws1.T, a2 = s_in@Ws2.T, c1 = h@Wkh.T
    short8 sf[4], hf[4];
#pragma unroll
    for (int kb = 0; kb < 4; ++kb) {
      sf[kb] = *(const short8*)&Sbuf[m][kb * 32 + q * 8];
      hf[kb] = *(const short8*)&Hbuf[m][kb * 32 + q * 8];
    }
    const f32x4 vzero = {0.0f, 0.0f, 0.0f, 0.0f};
    f32x4 a1[2] = {vzero, vzero}, a2[2] = {vzero, vzero}, c1a[2] = {vzero, vzero};
#pragma unroll
    for (int kb = 0; kb < 4; ++kb) {
#pragma unroll
      for (int T = 0; T < 2; ++T) {
        a1[T]  = __builtin_amdgcn_mfma_f32_16x16x32_bf16(sf[kb], wf[0][T][kb], a1[T], 0, 0, 0);
        a2[T]  = __builtin_amdgcn_mfma_f32_16x16x32_bf16(sf[kb], wf[1][T][kb], a2[T], 0, 0, 0);
        c1a[T] = __builtin_amdgcn_mfma_f32_16x16x32_bf16(hf[kb], wf[4][T][kb], c1a[T], 0, 0, 0);
      }
    }
#pragma unroll
    for (int T = 0; T < 2; ++T) {
      const int col = 32 * w + 16 * T + m;
#pragma unroll
      for (int i = 0; i < 4; ++i) {
        const float sg = fast_sigmoid(a1[T][i] + bs1v[T]);
        const float th = fast_tanh(a2[T][i] + bs2v[T]);
        Pbuf[q * 4 + i][col] = f2b(sg * th);
      }
    }
    wg_barrier_lds();

    // y_{t-1} finalize (uses pad written before the barrier)
    if (t > 0 && tid < 16) {
      const float d = *(const float*)&Pbuf[tid][128] + *(const float*)&Pbuf[tid][130] +
                      *(const float*)&Pbuf[tid][132] + *(const float*)&Pbuf[tid][134];
      outp[(size_t)(rbase + tid) * S_LEN + (t - 1)] = fast_sigmoid(d);
    }

    // phase B: p1 = sdf@Wp1s.T, p2 = sdf@Wp2s.T; gates; h update; dot partials
    short8 pf[4];
#pragma unroll
    for (int kb = 0; kb < 4; ++kb) pf[kb] = *(const short8*)&Pbuf[m][kb * 32 + q * 8];
    f32x4 p1a[2] = {vzero, vzero}, p2a[2] = {vzero, vzero};
#pragma unroll
    for (int kb = 0; kb < 4; ++kb) {
#pragma unroll
      for (int T = 0; T < 2; ++T) {
        p1a[T] = __builtin_amdgcn_mfma_f32_16x16x32_bf16(pf[kb], wf[2][T][kb], p1a[T], 0, 0, 0);
        p2a[T] = __builtin_amdgcn_mfma_f32_16x16x32_bf16(pf[kb], wf[3][T][kb], p2a[T], 0, 0, 0);
      }
    }
#pragma unroll
    for (int T = 0; T < 2; ++T) {
      const int col = 32 * w + 16 * T + m;
#pragma unroll
      for (int i = 0; i < 4; ++i) {
        const int row = q * 4 + i;
        const float gpre = b2f(ggb[t & 1][T][i]);
        const float g = fast_sigmoid(c1a[T][i] + gpre);
        const float t1 = cin_cur[i] ? tp1v[1][T] : tp1v[0][T];
        const float t2 = cin_cur[i] ? tp2v[1][T] : tp2v[0][T];
        const float pka = fast_sigmoid(p1a[T][i] + t1) * fast_tanh(p2a[T][i] + t2);
        const float hn = g * h[T][i] + (1.0f - g) * pka;
        h[T][i] = hn;
        const float xn = b2f(xnb[(t + 1) & 1][T][i]);
        if (T == 0) dotp[i] = xn * hn; else dotp[i] += xn * hn;
        Sbuf[row][col] = f2b(xn - hn);
        Hbuf[row][col] = f2b(hn);
      }
    }
#pragma unroll
    for (int i = 0; i < 4; ++i) cin_cur[i] = cin_nxt[i];
    wg_barrier_lds();
  }

  // epilogue: y_{S-2}
#pragma unroll
  for (int off = 1; off <= 8; off <<= 1) {
#pragma unroll
    for (int i = 0; i < 4; ++i) dotp[i] += __shfl_xor(dotp[i], off, 64);
  }
  if (m == 0) {
#pragma unroll
    for (int i = 0; i < 4; ++i) *(float*)&Pbuf[q * 4 + i][128 + 2 * w] = dotp[i];
  }
  wg_barrier_lds();
  if (tid < 16) {
    const float d = *(const float*)&Pbuf[tid][128] + *(const float*)&Pbuf[tid][130] +
                    *(const float*)&Pbuf[tid][132] + *(const float*)&Pbuf[tid][134];
    outp[(size_t)(rbase + tid) * S_LEN + (S_LEN - 2)] = fast_sigmoid(d);
  }
}

extern "C" void kernel_launch(void* const* d_in, const int* in_sizes, int n_in,
                              void* d_out, int out_size, void* d_ws, size_t ws_size,
                              hipStream_t stream) {
  const int* qs    = (const int*)d_in[0];
  const int* cs    = (const int*)d_in[1];
  const int* qds   = (const int*)d_in[2];
  const int* cds   = (const int*)d_in[3];
  const int* corr  = (const int*)d_in[4];
  const float* Eq    = (const float*)d_in[5];
  const float* Ec    = (const float*)d_in[6];
  const float* Eqd   = (const float*)d_in[7];
  const float* Ecd   = (const float*)d_in[8];
  const float* Ecorr = (const float*)d_in[9];
  const float* Wx  = (const float*)d_in[10];
  const float* bx  = (const float*)d_in[11];
  const float* Ws1 = (const float*)d_in[12];
  const float* bs1 = (const float*)d_in[13];
  const float* Ws2 = (const float*)d_in[14];
  const float* bs2 = (const float*)d_in[15];
  const float* Wp1 = (const float*)d_in[16];
  const float* bp1 = (const float*)d_in[17];
  const float* Wp2 = (const float*)d_in[18];
  const float* bp2 = (const float*)d_in[19];
  const float* Wk  = (const float*)d_in[20];
  const float* bk  = (const float*)d_in[21];
  const float* h0  = (const float*)d_in[22];

  char* ws = (char*)d_ws;
  // layout (with aliasing to cap ws use at ~104 MB):
  //   [0, 51.2MB)          X  [S][B][D] bf16
  //   [A, A+52.2MB)        GG [S-1][B][D] bf16  -- ALIASES the Tq/Tc/Tqd/Tcd
  //                        tables (13.1MB), which are dead after build_x.
  //   [A+52.2MB, ...)      small tables (Tkqd,Tkcd,Tkc,Tp1c,Tp2c)
  const size_t xbytes = (size_t)S_LEN * NBATCH * DIM * 2;          // 52,428,800
  const size_t A = (xbytes + 255) & ~(size_t)255;
  const size_t ggbytes = (size_t)(S_LEN - 1) * NBATCH * DIM * 2;   // 52,166,656
  unsigned short* X  = (unsigned short*)ws;
  unsigned short* GG = (unsigned short*)(ws + A);
  unsigned short* Tq  = GG;                                         // alias (build phase only)
  unsigned short* Tc  = (unsigned short*)(ws + A + (size_t)50000 * DIM * 2);
  unsigned short* Tqd = (unsigned short*)(ws + A + (size_t)51000 * DIM * 2);
  unsigned short* Tcd = (unsigned short*)(ws + A + (size_t)51101 * DIM * 2);
  size_t off = A + ((ggbytes + 255) & ~(size_t)255);
  auto alloc = [&](size_t bytes) {
    void* p = ws + off;
    off = (off + bytes + 255) & ~(size_t)255;
    return p;
  };
  unsigned short* Tkqd = (unsigned short*)alloc((size_t)101 * DIM * 2);
  unsigned short* Tkcd = (unsigned short*)alloc((size_t)101 * DIM * 2);
  float* Tkc  = (float*)alloc((size_t)2 * DIM * 4);
  float* Tp1c = (float*)alloc((size_t)2 * DIM * 4);
  float* Tp2c = (float*)alloc((size_t)2 * DIM * 4);

  proj_table_kernel<<<(50000 + 31) / 32, 256, 0, stream>>>(Eq, 50000, Wx, 512, 0, Tq);
  proj_table_kernel<<<(1000 + 31) / 32, 256, 0, stream>>>(Ec, 1000, Wx, 512, 128, Tc);
  proj_table_kernel<<<4, 256, 0, stream>>>(Eqd, 101, Wx, 512, 256, Tqd);
  proj_table_kernel<<<4, 256, 0, stream>>>(Ecd, 101, Wx, 512, 384, Tcd);
  small_tables_kernel<<<102, 256, 0, stream>>>(Eqd, Ecd, Ecorr, Wp1, bp1, Wp2, bp2, Wk, bk,
                                               Tkqd, Tkcd, Tkc, Tp1c, Tp2c);
  build_x_kernel<<<(S_LEN * NBATCH) / 16, 256, 0, stream>>>(qs, cs, qds, cds, Tq, Tc, Tqd, Tcd, bx, X);
  // after build_x, the Tq..Tcd region is dead -> GG may overwrite it
  build_gpre_kernel<<<((S_LEN - 1) * NBATCH) / 16, 256, 0, stream>>>(corr, qds, cds, Tkc, Tkqd, Tkcd, GG);
  scan_kernel<<<64, 256, 0, stream>>>(X, GG, h0, Ws1, bs1, Ws2, bs2, Wp1, Wp2, Wk,
                                      Tp1c, Tp2c, corr, (float*)d_out);
}

// Round 3
// 555.883 us; speedup vs baseline: 2.5694x; 2.5694x over previous
//
#include <hip/hip_runtime.h>

// DIMKT: B=1024, S=200, D=128.
// R3: scan = 64 blocks x 512 thr (8 waves x 16 cols), no Hbuf (h@Wk folded
// into precomputed gg stream via x@Wk GEMM), distance-2 register prefetch
// with STATIC indexing (unroll x2), lgkm-only barriers so prefetches stay
// in flight. Pre-kernels fused: proj_all, build_x, gemm_xwk, build_gpre_add.

#define S_LEN 200
#define NBATCH 1024
#define DIM 128
#define LOG2E 1.4426950408889634f

typedef short short8 __attribute__((ext_vector_type(8)));
typedef float f32x4 __attribute__((ext_vector_type(4)));

__device__ __forceinline__ unsigned short f2b(float f) {
  union { float f; unsigned u; } v; v.f = f;
  unsigned r = (v.u + 0x7FFFu + ((v.u >> 16) & 1u)) >> 16;  // RNE
  return (unsigned short)r;
}
__device__ __forceinline__ float b2f(unsigned short b) {
  union { unsigned u; float f; } v; v.u = ((unsigned)b) << 16;
  return v.f;
}
__device__ __forceinline__ float fast_sigmoid(float x) {
  return __builtin_amdgcn_rcpf(1.0f + __builtin_amdgcn_exp2f(-LOG2E * x));
}
__device__ __forceinline__ float fast_tanh(float x) {
  return 2.0f * __builtin_amdgcn_rcpf(1.0f + __builtin_amdgcn_exp2f(-2.0f * LOG2E * x)) - 1.0f;
}
// LDS-only barrier: does NOT drain vmcnt, so global prefetches stay in flight.
__device__ __forceinline__ void wg_barrier_lds() {
  __asm__ volatile("s_waitcnt lgkmcnt(0)\n\ts_barrier" ::: "memory");
}

// ---------------- P1 (fused): projected embedding tables + small tables.
// blocks [0,1563): Tq | [1563,1595): Tc | [1595,1599): Tqd | [1599,1603): Tcd
// [1603,1705): small tables
__global__ void proj_all_kernel(const float* __restrict__ Eq, const float* __restrict__ Ec,
                                const float* __restrict__ Eqd, const float* __restrict__ Ecd,
                                const float* __restrict__ Ecorr,
                                const float* __restrict__ Wx,
                                const float* __restrict__ Wp1, const float* __restrict__ bp1,
                                const float* __restrict__ Wp2, const float* __restrict__ bp2,
                                const float* __restrict__ Wk, const float* __restrict__ bk,
                                unsigned short* __restrict__ Tq, unsigned short* __restrict__ Tc,
                                unsigned short* __restrict__ Tqd, unsigned short* __restrict__ Tcd,
                                unsigned short* __restrict__ Tkqd, unsigned short* __restrict__ Tkcd,
                                float* __restrict__ Tkc, float* __restrict__ Tp1c,
                                float* __restrict__ Tp2c) {
  __shared__ __align__(16) float Elds[32][132];
  const int bid = blockIdx.x;
  const int tid = threadIdx.x;
  if (bid >= 1603) {
    const int blk = bid - 1603;
    if (blk < 101) {
      const int o = tid & 127, half = tid >> 7;
      const float* e = (half ? Ecd : Eqd) + (size_t)blk * DIM;
      const float* wr = Wk + (size_t)o * 512 + (half ? 384 : 256);
      float a = 0.f;
      for (int k = 0; k < DIM; ++k) a = fmaf(e[k], wr[k], a);
      (half ? Tkcd : Tkqd)[blk * DIM + o] = f2b(a);
    } else {
      for (int idx = tid; idx < 768; idx += 256) {
        const int t = idx >> 8, e = (idx >> 7) & 1, o = idx & 127;
        const float* ec = Ecorr + e * DIM;
        const float* wr; float bias; float* dst;
        if (t == 0)      { wr = Wp1 + (size_t)o * 256 + 128; bias = bp1[o]; dst = Tp1c; }
        else if (t == 1) { wr = Wp2 + (size_t)o * 256 + 128; bias = bp2[o]; dst = Tp2c; }
        else             { wr = Wk  + (size_t)o * 512 + 128; bias = bk[o];  dst = Tkc;  }
        float a = bias;
        for (int k = 0; k < DIM; ++k) a = fmaf(ec[k], wr[k], a);
        dst[e * DIM + o] = a;
      }
    }
    return;
  }
  const float* E; int M, coff, r0; unsigned short* T;
  if (bid < 1563)      { E = Eq;  M = 50000; coff = 0;   T = Tq;  r0 = bid * 32; }
  else if (bid < 1595) { E = Ec;  M = 1000;  coff = 128; T = Tc;  r0 = (bid - 1563) * 32; }
  else if (bid < 1599) { E = Eqd; M = 101;   coff = 256; T = Tqd; r0 = (bid - 1595) * 32; }
  else                 { E = Ecd; M = 101;   coff = 384; T = Tcd; r0 = (bid - 1599) * 32; }
  for (int idx = tid; idx < 32 * 32; idx += 256) {
    const int r = idx >> 5, c4 = idx & 31;
    float4 v = {0.f, 0.f, 0.f, 0.f};
    if (r0 + r < M) v = *(const float4*)(E + (size_t)(r0 + r) * DIM + c4 * 4);
    *(float4*)&Elds[r][c4 * 4] = v;
  }
  __syncthreads();
  const int o = tid & 127, rg = tid >> 7;
  const float* Wrow = Wx + (size_t)o * 512 + coff;
  float acc[16];
#pragma unroll
  for (int i = 0; i < 16; ++i) acc[i] = 0.f;
  for (int k4 = 0; k4 < 32; ++k4) {
    const float4 wv = *(const float4*)(Wrow + k4 * 4);
#pragma unroll
    for (int rr = 0; rr < 16; ++rr) {
      const float4 ev = *(const float4*)&Elds[rg * 16 + rr][k4 * 4];
      acc[rr] = fmaf(wv.x, ev.x, acc[rr]);
      acc[rr] = fmaf(wv.y, ev.y, acc[rr]);
      acc[rr] = fmaf(wv.z, ev.z, acc[rr]);
      acc[rr] = fmaf(wv.w, ev.w, acc[rr]);
    }
  }
#pragma unroll
  for (int rr = 0; rr < 16; ++rr) {
    const int r = r0 + rg * 16 + rr;
    if (r < M) T[(size_t)r * DIM + o] = f2b(acc[rr]);
  }
}

// ---------------- P2: x[s][b][:] = Tq[q]+Tc[c]+Tqd[qd]+Tcd[cd]+bx (bf16, s-major)
__global__ void build_x_kernel(const int* __restrict__ qs, const int* __restrict__ cs,
                               const int* __restrict__ qds, const int* __restrict__ cds,
                               const unsigned short* __restrict__ Tq, const unsigned short* __restrict__ Tc,
                               const unsigned short* __restrict__ Tqd, const unsigned short* __restrict__ Tcd,
                               const float* __restrict__ bx, unsigned short* __restrict__ xg) {
  const int r = blockIdx.x * 16 + (threadIdx.x >> 4);   // r = s*1024 + b
  const int c8 = (threadIdx.x & 15) * 8;
  const int s = r >> 10, b = r & 1023;
  const int q = qs[b * S_LEN + s], c = cs[b * S_LEN + s];
  const int qd = qds[b * S_LEN + s], cd = cds[b * S_LEN + s];
  union U8 { uint4 v; unsigned short s[8]; };
  U8 vq, vc, vd, ve, o;
  vq.v = *(const uint4*)(Tq + (size_t)q * DIM + c8);
  vc.v = *(const uint4*)(Tc + (size_t)c * DIM + c8);
  vd.v = *(const uint4*)(Tqd + (size_t)qd * DIM + c8);
  ve.v = *(const uint4*)(Tcd + (size_t)cd * DIM + c8);
  const float4 bx0 = *(const float4*)(bx + c8);
  const float4 bx1 = *(const float4*)(bx + c8 + 4);
  float bb[8] = {bx0.x, bx0.y, bx0.z, bx0.w, bx1.x, bx1.y, bx1.z, bx1.w};
#pragma unroll
  for (int j = 0; j < 8; ++j) {
    const float sv = b2f(vq.s[j]) + b2f(vc.s[j]) + b2f(vd.s[j]) + b2f(ve.s[j]) + bb[j];
    o.s[j] = f2b(sv);
  }
  *(uint4*)(xg + (size_t)r * DIM + c8) = o.v;
}

// ---------------- P2b: GG[r][n] = (x[r] @ Wk[:, :128].T)[n]  (bf16), r = t*1024+b
__global__ void gemm_xwk_kernel(const unsigned short* __restrict__ xg,
                                const float* __restrict__ Wk,
                                unsigned short* __restrict__ GG) {
  const int tid = threadIdx.x;
  const int w = tid >> 6, L = tid & 63, q = L >> 4, m = L & 15;
  const int rbase = blockIdx.x * 64;
  // B-frags of Wkh: n = 32w+16T+m, k = kb*32+q*8+j
  short8 wk[2][4];
#pragma unroll
  for (int T = 0; T < 2; ++T) {
    const int n = 32 * w + 16 * T + m;
#pragma unroll
    for (int kb = 0; kb < 4; ++kb) {
      const float* src = Wk + (size_t)n * 512 + kb * 32 + q * 8;
      const float4 v0 = *(const float4*)src;
      const float4 v1 = *(const float4*)(src + 4);
      short8 f;
      f[0] = (short)f2b(v0.x); f[1] = (short)f2b(v0.y);
      f[2] = (short)f2b(v0.z); f[3] = (short)f2b(v0.w);
      f[4] = (short)f2b(v1.x); f[5] = (short)f2b(v1.y);
      f[6] = (short)f2b(v1.z); f[7] = (short)f2b(v1.w);
      wk[T][kb] = f;
    }
  }
  const f32x4 vzero = {0.f, 0.f, 0.f, 0.f};
#pragma unroll
  for (int mt = 0; mt < 4; ++mt) {
    short8 af[4];
#pragma unroll
    for (int kb = 0; kb < 4; ++kb)
      af[kb] = *(const short8*)(xg + (size_t)(rbase + mt * 16 + m) * DIM + kb * 32 + q * 8);
    f32x4 acc[2] = {vzero, vzero};
#pragma unroll
    for (int kb = 0; kb < 4; ++kb) {
#pragma unroll
      for (int T = 0; T < 2; ++T)
        acc[T] = __builtin_amdgcn_mfma_f32_16x16x32_bf16(af[kb], wk[T][kb], acc[T], 0, 0, 0);
    }
#pragma unroll
    for (int T = 0; T < 2; ++T) {
      const int col = 32 * w + 16 * T + m;
#pragma unroll
      for (int i = 0; i < 4; ++i)
        GG[(size_t)(rbase + mt * 16 + q * 4 + i) * DIM + col] = f2b(acc[T][i]);
    }
  }
}

// ---------------- P2c: GG[t][b][:] += Tkc[corr](incl bk) + Tkqd[qd] + Tkcd[cd]
__global__ void build_gpre_add_kernel(const int* __restrict__ corr, const int* __restrict__ qds,
                                      const int* __restrict__ cds,
                                      const float* __restrict__ Tkc,
                                      const unsigned short* __restrict__ Tkqd,
                                      const unsigned short* __restrict__ Tkcd,
                                      unsigned short* __restrict__ gg) {
  const int r = blockIdx.x * 16 + (threadIdx.x >> 4);   // r = t*1024 + b, t<=198
  const int c8 = (threadIdx.x & 15) * 8;
  const int t = r >> 10, b = r & 1023;
  const int ci = corr[b * S_LEN + t], qi = qds[b * S_LEN + t], di = cds[b * S_LEN + t];
  union U8 { uint4 v; unsigned short s[8]; };
  U8 vq, vc, vg, o;
  vg.v = *(const uint4*)(gg + (size_t)r * DIM + c8);
  vq.v = *(const uint4*)(Tkqd + (size_t)qi * DIM + c8);
  vc.v = *(const uint4*)(Tkcd + (size_t)di * DIM + c8);
  const float4 k0 = *(const float4*)(Tkc + (size_t)ci * DIM + c8);
  const float4 k1 = *(const float4*)(Tkc + (size_t)ci * DIM + c8 + 4);
  float kk[8] = {k0.x, k0.y, k0.z, k0.w, k1.x, k1.y, k1.z, k1.w};
#pragma unroll
  for (int j = 0; j < 8; ++j)
    o.s[j] = f2b(b2f(vg.s[j]) + kk[j] + b2f(vq.s[j]) + b2f(vc.s[j]));
  *(uint4*)(gg + (size_t)r * DIM + c8) = o.v;
}

// ---------------- P3: the recurrence. 64 blocks x 512 thr (8 waves x 16 cols).
__global__ __launch_bounds__(512, 2) void scan_kernel(
    const unsigned short* __restrict__ xg,    // [S][B][D] bf16
    const unsigned short* __restrict__ gg,    // [S-1][B][D] bf16 (xWk + gate tables + bk)
    const float* __restrict__ h0,
    const float* __restrict__ Ws1, const float* __restrict__ bs1,
    const float* __restrict__ Ws2, const float* __restrict__ bs2,
    const float* __restrict__ Wp1, const float* __restrict__ Wp2,
    const float* __restrict__ Wk,
    const float* __restrict__ gTp1c, const float* __restrict__ gTp2c,
    const int* __restrict__ corr_seq,
    float* __restrict__ outp) {
  __shared__ __align__(16) unsigned short Sbuf[16][136];  // s_in (bf16)
  __shared__ __align__(16) unsigned short Pbuf[16][136];  // sdf (bf16)
  __shared__ float DotBuf[16][8];

  const int tid = threadIdx.x;
  const int w = tid >> 6, L = tid & 63, q = L >> 4, m = L & 15;
  const int col16 = 16 * w + m;          // this lane's feature column
  const int rbase = blockIdx.x << 4;

  // register-resident B-fragments: Ws1, Ws2, Wp1s, Wp2s, Wkh
  short8 wf[5][4];
  {
    const float* Wptr[5] = {Ws1, Ws2, Wp1, Wp2, Wk};
    const int ldw[5] = {128, 128, 256, 256, 512};
#pragma unroll
    for (int M = 0; M < 5; ++M) {
#pragma unroll
      for (int kb = 0; kb < 4; ++kb) {
        const float* src = Wptr[M] + (size_t)col16 * ldw[M] + kb * 32 + q * 8;
        const float4 v0 = *(const float4*)src;
        const float4 v1 = *(const float4*)(src + 4);
        short8 f;
        f[0] = (short)f2b(v0.x); f[1] = (short)f2b(v0.y);
        f[2] = (short)f2b(v0.z); f[3] = (short)f2b(v0.w);
        f[4] = (short)f2b(v1.x); f[5] = (short)f2b(v1.y);
        f[6] = (short)f2b(v1.z); f[7] = (short)f2b(v1.w);
        wf[M][kb] = f;
      }
    }
  }
  const float bs1v = bs1[col16], bs2v = bs2[col16];
  const float tp1v0 = gTp1c[col16], tp1v1 = gTp1c[DIM + col16];
  const float tp2v0 = gTp2c[col16], tp2v1 = gTp2c[DIM + col16];

  // init h (fp32 regs, C-layout rows q*4+i, col col16), Sbuf = x[0]-h
  float h[4];
#pragma unroll
  for (int i = 0; i < 4; ++i) {
    const int b = rbase + q * 4 + i;
    const float hv = h0[(size_t)b * DIM + col16];
    h[i] = hv;
    const float xt = b2f(xg[(size_t)b * DIM + col16]);  // s=0
    Sbuf[q * 4 + i][col16] = f2b(xt - hv);
  }
  if (tid < 16) outp[(size_t)(rbase + tid) * S_LEN + (S_LEN - 1)] = 0.0f;

  // distance-2 prefetch sets (STATIC indexing only)
  unsigned short xpA[4], ggA[4], xpB[4], ggB[4];
  int cpA[4], cpB[4];
#pragma unroll
  for (int i = 0; i < 4; ++i) {
    const int b = rbase + q * 4 + i;
    xpA[i] = xg[((size_t)1 * NBATCH + b) * DIM + col16];
    ggA[i] = gg[((size_t)0 * NBATCH + b) * DIM + col16];
    cpA[i] = corr_seq[b * S_LEN + 0];
    xpB[i] = xg[((size_t)2 * NBATCH + b) * DIM + col16];
    ggB[i] = gg[((size_t)1 * NBATCH + b) * DIM + col16];
    cpB[i] = corr_seq[b * S_LEN + 1];
  }
  float dotp[4] = {0.f, 0.f, 0.f, 0.f};
  const f32x4 vzero = {0.f, 0.f, 0.f, 0.f};

#define STEP(TCUR, XP, GP, CP)                                                 \
  do {                                                                         \
    const int t_ = (TCUR);                                                     \
    /* consume prefetches issued 2 steps ago */                                \
    float xnv[4], ggv[4];                                                      \
    int cin[4];                                                                \
    _Pragma("unroll") for (int i = 0; i < 4; ++i) {                            \
      xnv[i] = b2f(XP[i]);                                                     \
      ggv[i] = b2f(GP[i]);                                                     \
      cin[i] = CP[i];                                                          \
    }                                                                          \
    /* reissue this set for t+2 */                                             \
    {                                                                          \
      const int tp_ = (t_ + 2 <= 198) ? t_ + 2 : 198;                          \
      _Pragma("unroll") for (int i = 0; i < 4; ++i) {                          \
        const int b = rbase + q * 4 + i;                                       \
        XP[i] = xg[((size_t)(tp_ + 1) * NBATCH + b) * DIM + col16];            \
        GP[i] = gg[((size_t)tp_ * NBATCH + b) * DIM + col16];                  \
        CP[i] = corr_seq[b * S_LEN + tp_];                                     \
      }                                                                        \
    }                                                                          \
    /* deferred y_{t-1}: reduce prev dot partials over 16 m-lanes */           \
    {                                                                          \
      float dr0 = dotp[0], dr1 = dotp[1], dr2 = dotp[2], dr3 = dotp[3];        \
      _Pragma("unroll") for (int off = 1; off <= 8; off <<= 1) {               \
        dr0 += __shfl_xor(dr0, off, 64);                                       \
        dr1 += __shfl_xor(dr1, off, 64);                                       \
        dr2 += __shfl_xor(dr2, off, 64);                                       \
        dr3 += __shfl_xor(dr3, off, 64);                                       \
      }                                                                        \
      if (m == 0) {                                                            \
        DotBuf[q * 4 + 0][w] = dr0;                                            \
        DotBuf[q * 4 + 1][w] = dr1;                                            \
        DotBuf[q * 4 + 2][w] = dr2;                                            \
        DotBuf[q * 4 + 3][w] = dr3;                                            \
      }                                                                        \
    }                                                                          \
    wg_barrier_lds(); /* BAR1: Sbuf(t-1) + DotBuf visible */                   \
    if (t_ > 0 && tid < 16) {                                                  \
      float d = 0.f;                                                           \
      _Pragma("unroll") for (int ww = 0; ww < 8; ++ww) d += DotBuf[tid][ww];   \
      outp[(size_t)(rbase + tid) * S_LEN + (t_ - 1)] = fast_sigmoid(d);        \
    }                                                                          \
    /* phase A: a1 = s@Ws1.T, a2 = s@Ws2.T, c1 = s@Wkh.T */                    \
    short8 sf[4];                                                              \
    _Pragma("unroll") for (int kb = 0; kb < 4; ++kb)                           \
        sf[kb] = *(const short8*)&Sbuf[m][kb * 32 + q * 8];                    \
    f32x4 a1 = vzero, a2 = vzero, c1 = vzero;                                  \
    _Pragma("unroll") for (int kb = 0; kb < 4; ++kb) {                         \
      a1 = __builtin_amdgcn_mfma_f32_16x16x32_bf16(sf[kb], wf[0][kb], a1, 0, 0, 0); \
      a2 = __builtin_amdgcn_mfma_f32_16x16x32_bf16(sf[kb], wf[1][kb], a2, 0, 0, 0); \
      c1 = __builtin_amdgcn_mfma_f32_16x16x32_bf16(sf[kb], wf[4][kb], c1, 0, 0, 0); \
    }                                                                          \
    _Pragma("unroll") for (int i = 0; i < 4; ++i) {                            \
      const float sg = fast_sigmoid(a1[i] + bs1v);                             \
      const float th = fast_tanh(a2[i] + bs2v);                                \
      Pbuf[q * 4 + i][col16] = f2b(sg * th);                                   \
    }                                                                          \
    wg_barrier_lds(); /* BAR2: Pbuf visible */                                 \
    /* phase B: p1 = sdf@Wp1s.T, p2 = sdf@Wp2s.T; gates; h; dot; s_in(t+1) */  \
    short8 pf[4];                                                              \
    _Pragma("unroll") for (int kb = 0; kb < 4; ++kb)                           \
        pf[kb] = *(const short8*)&Pbuf[m][kb * 32 + q * 8];                    \
    f32x4 p1 = vzero, p2 = vzero;                                              \
    _Pragma("unroll") for (int kb = 0; kb < 4; ++kb) {                         \
      p1 = __builtin_amdgcn_mfma_f32_16x16x32_bf16(pf[kb], wf[2][kb], p1, 0, 0, 0); \
      p2 = __builtin_amdgcn_mfma_f32_16x16x32_bf16(pf[kb], wf[3][kb], p2, 0, 0, 0); \
    }                                                                          \
    _Pragma("unroll") for (int i = 0; i < 4; ++i) {                            \
      const float g = fast_sigmoid(ggv[i] - c1[i]);                            \
      const float t1 = cin[i] ? tp1v1 : tp1v0;                                 \
      const float t2 = cin[i] ? tp2v1 : tp2v0;                                 \
      const float pka = fast_sigmoid(p1[i] + t1) * fast_tanh(p2[i] + t2);      \
      const float hn = g * h[i] + (1.0f - g) * pka;                            \
      h[i] = hn;                                                               \
      dotp[i] = xnv[i] * hn;                                                   \
      Sbuf[q * 4 + i][col16] = f2b(xnv[i] - hn);                               \
    }                                                                          \
  } while (0)

  for (int t2 = 0; t2 < 198; t2 += 2) {
    STEP(t2, xpA, ggA, cpA);
    STEP(t2 + 1, xpB, ggB, cpB);
  }
  STEP(198, xpA, ggA, cpA);
#undef STEP

  // epilogue: y_{198}
  {
    float dr0 = dotp[0], dr1 = dotp[1], dr2 = dotp[2], dr3 = dotp[3];
#pragma unroll
    for (int off = 1; off <= 8; off <<= 1) {
      dr0 += __shfl_xor(dr0, off, 64);
      dr1 += __shfl_xor(dr1, off, 64);
      dr2 += __shfl_xor(dr2, off, 64);
      dr3 += __shfl_xor(dr3, off, 64);
    }
    if (m == 0) {
      DotBuf[q * 4 + 0][w] = dr0;
      DotBuf[q * 4 + 1][w] = dr1;
      DotBuf[q * 4 + 2][w] = dr2;
      DotBuf[q * 4 + 3][w] = dr3;
    }
  }
  wg_barrier_lds();
  if (tid < 16) {
    float d = 0.f;
#pragma unroll
    for (int ww = 0; ww < 8; ++ww) d += DotBuf[tid][ww];
    outp[(size_t)(rbase + tid) * S_LEN + (S_LEN - 2)] = fast_sigmoid(d);
  }
}

extern "C" void kernel_launch(void* const* d_in, const int* in_sizes, int n_in,
                              void* d_out, int out_size, void* d_ws, size_t ws_size,
                              hipStream_t stream) {
  const int* qs    = (const int*)d_in[0];
  const int* cs    = (const int*)d_in[1];
  const int* qds   = (const int*)d_in[2];
  const int* cds   = (const int*)d_in[3];
  const int* corr  = (const int*)d_in[4];
  const float* Eq    = (const float*)d_in[5];
  const float* Ec    = (const float*)d_in[6];
  const float* Eqd   = (const float*)d_in[7];
  const float* Ecd   = (const float*)d_in[8];
  const float* Ecorr = (const float*)d_in[9];
  const float* Wx  = (const float*)d_in[10];
  const float* bx  = (const float*)d_in[11];
  const float* Ws1 = (const float*)d_in[12];
  const float* bs1 = (const float*)d_in[13];
  const float* Ws2 = (const float*)d_in[14];
  const float* bs2 = (const float*)d_in[15];
  const float* Wp1 = (const float*)d_in[16];
  const float* bp1 = (const float*)d_in[17];
  const float* Wp2 = (const float*)d_in[18];
  const float* bp2 = (const float*)d_in[19];
  const float* Wk  = (const float*)d_in[20];
  const float* bk  = (const float*)d_in[21];
  const float* h0  = (const float*)d_in[22];

  char* ws = (char*)d_ws;
  // layout: [0, 52.4MB) X | [A, A+52.2MB) GG (aliases Tq..Tcd, dead after
  // build_x) | then small tables.
  const size_t xbytes = (size_t)S_LEN * NBATCH * DIM * 2;
  const size_t A = (xbytes + 255) & ~(size_t)255;
  const size_t ggbytes = (size_t)(S_LEN - 1) * NBATCH * DIM * 2;
  unsigned short* X  = (unsigned short*)ws;
  unsigned short* GG = (unsigned short*)(ws + A);
  unsigned short* Tq  = GG;  // alias (build phase only)
  unsigned short* Tc  = (unsigned short*)(ws + A + (size_t)50000 * DIM * 2);
  unsigned short* Tqd = (unsigned short*)(ws + A + (size_t)51000 * DIM * 2);
  unsigned short* Tcd = (unsigned short*)(ws + A + (size_t)51101 * DIM * 2);
  size_t off = A + ((ggbytes + 255) & ~(size_t)255);
  auto alloc = [&](size_t bytes) {
    void* p = ws + off;
    off = (off + bytes + 255) & ~(size_t)255;
    return p;
  };
  unsigned short* Tkqd = (unsigned short*)alloc((size_t)101 * DIM * 2);
  unsigned short* Tkcd = (unsigned short*)alloc((size_t)101 * DIM * 2);
  float* Tkc  = (float*)alloc((size_t)2 * DIM * 4);
  float* Tp1c = (float*)alloc((size_t)2 * DIM * 4);
  float* Tp2c = (float*)alloc((size_t)2 * DIM * 4);

  proj_all_kernel<<<1705, 256, 0, stream>>>(Eq, Ec, Eqd, Ecd, Ecorr, Wx,
                                            Wp1, bp1, Wp2, bp2, Wk, bk,
                                            Tq, Tc, Tqd, Tcd, Tkqd, Tkcd, Tkc, Tp1c, Tp2c);
  build_x_kernel<<<(S_LEN * NBATCH) / 16, 256, 0, stream>>>(qs, cs, qds, cds, Tq, Tc, Tqd, Tcd, bx, X);
  // Tq..Tcd dead now -> GG overwrites them
  gemm_xwk_kernel<<<((S_LEN - 1) * NBATCH) / 64, 256, 0, stream>>>(X, Wk, GG);
  build_gpre_add_kernel<<<((S_LEN - 1) * NBATCH) / 16, 256, 0, stream>>>(corr, qds, cds, Tkc, Tkqd, Tkcd, GG);
  scan_kernel<<<64, 512, 0, stream>>>(X, GG, h0, Ws1, bs1, Ws2, bs2, Wp1, Wp2, Wk,
                                      Tp1c, Tp2c, corr, (float*)d_out);
}